// Round 1
// baseline (950.672 us; speedup 1.0000x reference)
//
#include <hip/hip_runtime.h>

#define SEQ 2048
#define NVAR 64
#define DMODEL 512
#define BSZ 128
#define KC 64
#define NPT (BSZ*NVAR)   /* 8192 points */
#define MAXIT 10

// ---------------------------------------------------------------------------
// init: cent_cur = centroids, cent_sq[k] = ||cent_k||^2, zero flags/counters
// grid 64, block 256
// ---------------------------------------------------------------------------
__global__ __launch_bounds__(256) void init_k(const float* __restrict__ c0,
    float* __restrict__ cent, float* __restrict__ cent_sq, int* __restrict__ done,
    float* __restrict__ shift2, int* __restrict__ ticket) {
  const int k = blockIdx.x, t = threadIdx.x;
  __shared__ float red[256];
  float l = 0.f;
  #pragma unroll
  for (int rr = 0; rr < 2; ++rr) {
    int d = t + 256 * rr;
    float v = c0[k * DMODEL + d];
    cent[k * DMODEL + d] = v;
    l += v * v;
  }
  red[t] = l; __syncthreads();
  for (int s = 128; s > 0; s >>= 1) { if (t < s) red[t] += red[t + s]; __syncthreads(); }
  if (t == 0) cent_sq[k] = red[0];
  if (k == 0 && t < MAXIT) { shift2[t] = 0.f; ticket[t] = 0; }
  if (k == 0 && t == 31) *done = 0;
}

// ---------------------------------------------------------------------------
// gemm_emb: emb[bs*64+m][n] = sum_k x[bs][k][m] * W[n][k] + b[n]
// grid (4 n-tiles, 128 bs), block 256.  Tile 64m x 128n, K-tile 64.
// ---------------------------------------------------------------------------
__global__ __launch_bounds__(256) void gemm_emb(const float* __restrict__ x,
    const float* __restrict__ W, const float* __restrict__ bias,
    float* __restrict__ emb) {
  __shared__ float As[64][64];    // [k][m], direct copy of x rows
  __shared__ float Ws[64][132];   // [k][n], pad 132: transpose-store 2-way only
  const int bs = blockIdx.y;
  const int n0 = blockIdx.x * 128;
  const int t = threadIdx.x;
  const int tx = t & 15;   // n = 8*tx
  const int ty = t >> 4;   // m = 4*ty

  float bv[8];
  #pragma unroll
  for (int j = 0; j < 8; ++j) bv[j] = bias[n0 + 8 * tx + j];
  float acc[4][8];
  #pragma unroll
  for (int i = 0; i < 4; ++i)
    #pragma unroll
    for (int j = 0; j < 8; ++j) acc[i][j] = 0.f;

  const float* xb = x + (size_t)bs * SEQ * NVAR;

  for (int k0 = 0; k0 < SEQ; k0 += 64) {
    __syncthreads();
    {
      const float4* src = (const float4*)(xb + (size_t)k0 * NVAR);
      float4* dst = (float4*)&As[0][0];
      #pragma unroll
      for (int r = 0; r < 4; ++r) dst[t + 256 * r] = src[t + 256 * r];
    }
    #pragma unroll
    for (int r = 0; r < 8; ++r) {
      int idx = t + 256 * r;
      int k4 = idx & 15, n = idx >> 4;
      float4 w = *(const float4*)(W + (size_t)(n0 + n) * SEQ + k0 + 4 * k4);
      Ws[4 * k4 + 0][n] = w.x; Ws[4 * k4 + 1][n] = w.y;
      Ws[4 * k4 + 2][n] = w.z; Ws[4 * k4 + 3][n] = w.w;
    }
    __syncthreads();
    #pragma unroll 8
    for (int kk = 0; kk < 64; ++kk) {
      const float4 a  = *(const float4*)&As[kk][4 * ty];
      const float4 w0 = *(const float4*)&Ws[kk][8 * tx];
      const float4 w1 = *(const float4*)&Ws[kk][8 * tx + 4];
      const float av[4] = {a.x, a.y, a.z, a.w};
      const float wv[8] = {w0.x, w0.y, w0.z, w0.w, w1.x, w1.y, w1.z, w1.w};
      #pragma unroll
      for (int i = 0; i < 4; ++i)
        #pragma unroll
        for (int j = 0; j < 8; ++j)
          acc[i][j] = fmaf(av[i], wv[j], acc[i][j]);
    }
  }
  #pragma unroll
  for (int i = 0; i < 4; ++i) {
    int row = bs * NVAR + 4 * ty + i;
    float4 o0 = make_float4(acc[i][0] + bv[0], acc[i][1] + bv[1],
                            acc[i][2] + bv[2], acc[i][3] + bv[3]);
    float4 o1 = make_float4(acc[i][4] + bv[4], acc[i][5] + bv[5],
                            acc[i][6] + bv[6], acc[i][7] + bv[7]);
    *(float4*)(emb + (size_t)row * DMODEL + n0 + 8 * tx) = o0;
    *(float4*)(emb + (size_t)row * DMODEL + n0 + 8 * tx + 4) = o1;
  }
}

// ---------------------------------------------------------------------------
// assign_partial: partial[c][k][n] = sum_{d in chunk c} emb[n][d]*cent[k][d]
// grid (32 pt-tiles, 8 d-chunks of 64), block 256.  256pt x 64cl per block.
// ---------------------------------------------------------------------------
__global__ __launch_bounds__(256) void assign_partial(const float* __restrict__ emb,
    const float* __restrict__ cent, const int* __restrict__ done,
    float* __restrict__ partial) {
  if (*done) return;
  __shared__ float Es[32][268];  // [d][p], stride 268: 16B aligned, 2-way store
  __shared__ float Cs[32][76];   // [d][k]
  const int p0 = blockIdx.x * 256;
  const int d0 = blockIdx.y * 64;
  const int t = threadIdx.x;
  const int ty = t & 31;   // p = 8*ty
  const int tx = t >> 5;   // k = 8*tx

  float acc[8][8];
  #pragma unroll
  for (int i = 0; i < 8; ++i)
    #pragma unroll
    for (int j = 0; j < 8; ++j) acc[i][j] = 0.f;

  for (int sd = 0; sd < 64; sd += 32) {
    __syncthreads();
    #pragma unroll
    for (int r = 0; r < 8; ++r) {
      int idx = t + 256 * r;
      int d4 = idx & 7, p = idx >> 3;
      float4 e = *(const float4*)(emb + (size_t)(p0 + p) * DMODEL + d0 + sd + 4 * d4);
      Es[4 * d4 + 0][p] = e.x; Es[4 * d4 + 1][p] = e.y;
      Es[4 * d4 + 2][p] = e.z; Es[4 * d4 + 3][p] = e.w;
    }
    #pragma unroll
    for (int r = 0; r < 2; ++r) {
      int idx = t + 256 * r;
      int d4 = idx & 7, k = idx >> 3;
      float4 c = *(const float4*)(cent + (size_t)k * DMODEL + d0 + sd + 4 * d4);
      Cs[4 * d4 + 0][k] = c.x; Cs[4 * d4 + 1][k] = c.y;
      Cs[4 * d4 + 2][k] = c.z; Cs[4 * d4 + 3][k] = c.w;
    }
    __syncthreads();
    #pragma unroll 4
    for (int dd = 0; dd < 32; ++dd) {
      const float4 e0 = *(const float4*)&Es[dd][8 * ty];
      const float4 e1 = *(const float4*)&Es[dd][8 * ty + 4];
      const float4 c0 = *(const float4*)&Cs[dd][8 * tx];
      const float4 c1 = *(const float4*)&Cs[dd][8 * tx + 4];
      const float ev[8] = {e0.x, e0.y, e0.z, e0.w, e1.x, e1.y, e1.z, e1.w};
      const float cv[8] = {c0.x, c0.y, c0.z, c0.w, c1.x, c1.y, c1.z, c1.w};
      #pragma unroll
      for (int i = 0; i < 8; ++i)
        #pragma unroll
        for (int j = 0; j < 8; ++j)
          acc[i][j] = fmaf(ev[i], cv[j], acc[i][j]);
    }
  }
  float* pb = partial + (size_t)blockIdx.y * (KC * NPT) + p0 + 8 * ty;
  #pragma unroll
  for (int j = 0; j < 8; ++j) {
    int k = 8 * tx + j;
    float4 v0 = make_float4(acc[0][j], acc[1][j], acc[2][j], acc[3][j]);
    float4 v1 = make_float4(acc[4][j], acc[5][j], acc[6][j], acc[7][j]);
    *(float4*)(pb + (size_t)k * NPT) = v0;
    *(float4*)(pb + (size_t)k * NPT + 4) = v1;
  }
}

// ---------------------------------------------------------------------------
// argmin_segsum: ids = argmin_k(csq[k]-2*dot), deterministic per-block segsum
// grid 64 (128 points each), block 256.
// ---------------------------------------------------------------------------
__global__ __launch_bounds__(256) void argmin_segsum(const float* __restrict__ partial,
    const float* __restrict__ cent_sq, const float* __restrict__ emb,
    const int* __restrict__ done, int* __restrict__ ids,
    float* __restrict__ psum, float* __restrict__ pcnt) {
  if (*done) return;
  __shared__ float sums[KC][DMODEL];   // 128 KB
  __shared__ int ids_l[128];
  const int g = blockIdx.x, t = threadIdx.x;
  const int p0 = g * 128;

  if (t >= 128) {
    // zero the LDS accumulator (other half does argmin concurrently)
    float4 z = make_float4(0.f, 0.f, 0.f, 0.f);
    float4* sz = (float4*)&sums[0][0];
    #pragma unroll
    for (int r = 0; r < 64; ++r) sz[(t - 128) + 128 * r] = z;
  } else {
    int p = p0 + t;
    float best = 1e30f; int bi = 0;
    for (int k = 0; k < KC; ++k) {
      float dot = 0.f;
      #pragma unroll
      for (int c = 0; c < 8; ++c)
        dot += partial[(size_t)c * (KC * NPT) + (size_t)k * NPT + p];
      float d2 = cent_sq[k] - 2.f * dot;
      if (d2 < best) { best = d2; bi = k; }
    }
    ids[p] = bi;
    ids_l[t] = bi;
  }
  __syncthreads();

  // deterministic accumulation: thread owns dims 2t,2t+1; sequential points
  const int d0 = 2 * t;
  for (int p = 0; p < 128; ++p) {
    int id = ids_l[p];
    float2 e = *(const float2*)(emb + (size_t)(p0 + p) * DMODEL + d0);
    float2* s = (float2*)&sums[id][d0];
    float2 v = *s;
    v.x += e.x; v.y += e.y;
    *s = v;
  }
  __syncthreads();
  for (int k = 0; k < KC; ++k)
    *(float2*)(psum + ((size_t)g * KC + k) * DMODEL + d0) = *(const float2*)&sums[k][d0];
  if (t < KC) {
    int c = 0;
    for (int p = 0; p < 128; ++p) c += (ids_l[p] == t);
    pcnt[g * KC + t] = (float)c;
  }
}

// ---------------------------------------------------------------------------
// update_cent: reduce partials (fixed order), new centroids, shift, done flag,
// cent_sq for next iter.  grid 64 (one cluster each), block 256.
// ---------------------------------------------------------------------------
__global__ __launch_bounds__(256) void update_cent(float* __restrict__ cent,
    const float* __restrict__ psum, const float* __restrict__ pcnt,
    int* __restrict__ done, float* __restrict__ cent_sq,
    float* __restrict__ shift2, int* __restrict__ ticket, int iter) {
  if (*done) return;
  const int k = blockIdx.x, t = threadIdx.x;
  __shared__ float red[256];
  __shared__ float cnt_s;
  if (t < 64) {
    float c = pcnt[t * KC + k];
    #pragma unroll
    for (int off = 32; off > 0; off >>= 1) c += __shfl_down(c, off, 64);
    if (t == 0) cnt_s = c;
  }
  __syncthreads();
  const float count = cnt_s;
  float l_sh = 0.f, l_sq = 0.f;
  #pragma unroll
  for (int rr = 0; rr < 2; ++rr) {
    int d = t + 256 * rr;
    float s = 0.f;
    for (int g = 0; g < 64; ++g)            // fixed order: deterministic
      s += psum[((size_t)g * KC + k) * DMODEL + d];
    float oldv = cent[k * DMODEL + d];
    float newv = (count > 0.f) ? (s / fmaxf(count, 1.f)) : oldv;
    cent[k * DMODEL + d] = newv;
    float df = newv - oldv;
    l_sh += df * df;
    l_sq += newv * newv;
  }
  red[t] = l_sh; __syncthreads();
  for (int s = 128; s > 0; s >>= 1) { if (t < s) red[t] += red[t + s]; __syncthreads(); }
  float tot_sh = red[0]; __syncthreads();
  red[t] = l_sq; __syncthreads();
  for (int s = 128; s > 0; s >>= 1) { if (t < s) red[t] += red[t + s]; __syncthreads(); }
  if (t == 0) {
    cent_sq[k] = red[0];
    atomicAdd(shift2 + iter, tot_sh);
    __threadfence();
    int tk = atomicAdd(ticket + iter, 1);
    if (tk == 63) {
      float tot = atomicAdd(shift2 + iter, 0.f);   // all adds ordered before tickets
      if (sqrtf(tot) < 1e-4f) *done = 1;
    }
  }
}

// ---------------------------------------------------------------------------
// finalize: one-hot prob + copy centroids.  grid 2176, block 256.
// ---------------------------------------------------------------------------
__global__ __launch_bounds__(256) void finalize_k(const int* __restrict__ ids,
    const float* __restrict__ cent, float* __restrict__ out) {
  int t = blockIdx.x * 256 + threadIdx.x;
  if (t < NPT * KC) {
    int n = t >> 6, k = t & 63;
    out[t] = (ids[n] == k) ? 1.f : 0.f;
  } else {
    int i = t - NPT * KC;
    if (i < KC * DMODEL) out[NPT * KC + i] = cent[i];
  }
}

// ---------------------------------------------------------------------------
extern "C" void kernel_launch(void* const* d_in, const int* in_sizes, int n_in,
                              void* d_out, int out_size, void* d_ws, size_t ws_size,
                              hipStream_t stream) {
  const float* x    = (const float*)d_in[0];   // [128,2048,64]
  const float* W    = (const float*)d_in[1];   // [512,2048]
  const float* bias = (const float*)d_in[2];   // [512]
  const float* c0   = (const float*)d_in[3];   // [64,512]
  float* out = (float*)d_out;

  // output layout: prob [8192*64] | cent [64*512] | x_emb [8192*512]
  float* emb_out  = out + NPT * KC + KC * DMODEL;  // 557056
  float* cent_out = out + NPT * KC;                 // 524288

  // workspace layout (floats)
  float* w = (float*)d_ws;
  float* cent    = w;                       // 32768
  float* cent_sq = w + 32768;               // 64
  float* shift2  = w + 32832;               // 16
  float* pcnt    = w + 32848;               // 4096
  int*   done_f  = (int*)(w + 36944);       // 16 (1 used)
  int*   ticket  = (int*)(w + 36960);       // 16
  int*   ids     = (int*)(w + 36976);       // 8192
  float* partial = w + 45168;               // 8*64*8192 = 4194304
  float* psum    = w + 45168 + 4194304;     // 64*64*512 = 2097152
  (void)ws_size; (void)n_in; (void)in_sizes; (void)out_size;

  init_k<<<KC, 256, 0, stream>>>(c0, cent, cent_sq, done_f, shift2, ticket);
  gemm_emb<<<dim3(4, BSZ), 256, 0, stream>>>(x, W, bias, emb_out);
  for (int it = 0; it < MAXIT; ++it) {
    assign_partial<<<dim3(32, 8), 256, 0, stream>>>(emb_out, cent, done_f, partial);
    argmin_segsum<<<KC, 256, 0, stream>>>(partial, cent_sq, emb_out, done_f,
                                          ids, psum, pcnt);
    update_cent<<<KC, 256, 0, stream>>>(cent, psum, pcnt, done_f, cent_sq,
                                        shift2, ticket, it);
  }
  finalize_k<<<2176, 256, 0, stream>>>(ids, cent, out);
}

// Round 2
// 828.192 us; speedup vs baseline: 1.1479x; 1.1479x over previous
//
#include <hip/hip_runtime.h>

#define SEQ 2048
#define NVAR 64
#define DMODEL 512
#define BSZ 128
#define KC 64
#define NPT (BSZ*NVAR)   /* 8192 points */
#define MAXIT 10

typedef __bf16 bf16x8 __attribute__((ext_vector_type(8)));
typedef float f32x4 __attribute__((ext_vector_type(4)));

__device__ __forceinline__ void load_lds16(const void* g, void* l) {
  __builtin_amdgcn_global_load_lds((const __attribute__((address_space(1))) void*)g,
                                   (__attribute__((address_space(3))) void*)l, 16, 0, 0);
}

__device__ __forceinline__ unsigned short bf16_rn(float x) {
  unsigned int u = __float_as_uint(x);
  u += 0x7fffu + ((u >> 16) & 1u);
  return (unsigned short)(u >> 16);
}

// ---------------------------------------------------------------------------
// init: cent_cur = centroids, cent_sq[k] = ||cent_k||^2, zero flags/counters
// ---------------------------------------------------------------------------
__global__ __launch_bounds__(256) void init_k(const float* __restrict__ c0,
    float* __restrict__ cent, float* __restrict__ cent_sq, int* __restrict__ done,
    float* __restrict__ shift2, int* __restrict__ ticket) {
  const int k = blockIdx.x, t = threadIdx.x;
  __shared__ float red[256];
  float l = 0.f;
  #pragma unroll
  for (int rr = 0; rr < 2; ++rr) {
    int d = t + 256 * rr;
    float v = c0[k * DMODEL + d];
    cent[k * DMODEL + d] = v;
    l += v * v;
  }
  red[t] = l; __syncthreads();
  for (int s = 128; s > 0; s >>= 1) { if (t < s) red[t] += red[t + s]; __syncthreads(); }
  if (t == 0) cent_sq[k] = red[0];
  if (k == 0 && t < MAXIT) { shift2[t] = 0.f; ticket[t] = 0; }
  if (k == 0 && t == 31) *done = 0;
}

// ---------------------------------------------------------------------------
// conv_w: W[512][2048] fp32 -> W_hi/W_lo bf16 (same layout).  grid 1024x256.
// ---------------------------------------------------------------------------
__global__ __launch_bounds__(256) void conv_w(const float* __restrict__ W,
    unsigned short* __restrict__ Wh, unsigned short* __restrict__ Wl) {
  int i = (blockIdx.x * 256 + threadIdx.x) * 4;
  float4 v = *(const float4*)(W + i);
  ushort4 h, l;
  h.x = bf16_rn(v.x); l.x = bf16_rn(v.x - __uint_as_float((unsigned)h.x << 16));
  h.y = bf16_rn(v.y); l.y = bf16_rn(v.y - __uint_as_float((unsigned)h.y << 16));
  h.z = bf16_rn(v.z); l.z = bf16_rn(v.z - __uint_as_float((unsigned)h.z << 16));
  h.w = bf16_rn(v.w); l.w = bf16_rn(v.w - __uint_as_float((unsigned)h.w << 16));
  *(ushort4*)(Wh + i) = h;
  *(ushort4*)(Wl + i) = l;
}

// ---------------------------------------------------------------------------
// conv_x: x[bs][k][v] -> xt_hi/lo[bs*64+v][k] bf16.  grid (32 ktiles,128 bs).
// ---------------------------------------------------------------------------
__global__ __launch_bounds__(256) void conv_x(const float* __restrict__ x,
    unsigned short* __restrict__ Xh, unsigned short* __restrict__ Xl) {
  __shared__ float tile[64 * 65];
  const int k0 = blockIdx.x * 64;
  const int bs = blockIdx.y;
  const int t = threadIdx.x;
  const float* xb = x + (size_t)bs * SEQ * NVAR + (size_t)k0 * NVAR;
  #pragma unroll
  for (int p = 0; p < 4; ++p) {
    int idx = t + 256 * p;
    int row = idx >> 4, c4 = (idx & 15) * 4;
    float4 v = *(const float4*)(xb + row * NVAR + c4);
    tile[row * 65 + c4 + 0] = v.x; tile[row * 65 + c4 + 1] = v.y;
    tile[row * 65 + c4 + 2] = v.z; tile[row * 65 + c4 + 3] = v.w;
  }
  __syncthreads();
  const int v = t >> 2;            // 0..63
  const int kc = (t & 3) * 16;     // 0,16,32,48
  unsigned short h[16], l[16];
  #pragma unroll
  for (int j = 0; j < 16; ++j) {
    float f = tile[(kc + j) * 65 + v];
    h[j] = bf16_rn(f);
    l[j] = bf16_rn(f - __uint_as_float((unsigned)h[j] << 16));
  }
  size_t off = (size_t)(bs * 64 + v) * SEQ + k0 + kc;
  *(uint4*)(Xh + off)     = *(uint4*)&h[0];
  *(uint4*)(Xh + off + 8) = *(uint4*)&h[8];
  *(uint4*)(Xl + off)     = *(uint4*)&l[0];
  *(uint4*)(Xl + off + 8) = *(uint4*)&l[8];
}

// ---------------------------------------------------------------------------
// gemm_mfma: emb[m][n] = sum_k xt[m][k]*W[n][k] + b[n], bf16x3 split MFMA.
// grid (4 n, 64 m), 256 threads (4 waves, 2x2 of 64x64 wave tiles), BK=64.
// LDS chunk-swizzle: 16B chunk c of row r stored at slot c^(r&7).
// ---------------------------------------------------------------------------
__global__ __launch_bounds__(256) void gemm_mfma(
    const unsigned short* __restrict__ Ah, const unsigned short* __restrict__ Al,
    const unsigned short* __restrict__ Bh, const unsigned short* __restrict__ Bl,
    const float* __restrict__ bias, float* __restrict__ emb) {
  __shared__ unsigned short sAh[128 * 64] __attribute__((aligned(16)));
  __shared__ unsigned short sAl[128 * 64] __attribute__((aligned(16)));
  __shared__ unsigned short sBh[128 * 64] __attribute__((aligned(16)));
  __shared__ unsigned short sBl[128 * 64] __attribute__((aligned(16)));
  const int t = threadIdx.x;
  const int w = t >> 6, lane = t & 63;
  const int m0 = blockIdx.y * 128;
  const int n0 = blockIdx.x * 128;
  const int wm = (w >> 1) * 64, wn = (w & 1) * 64;
  const int lrow = lane >> 3;                    // 0..7
  const int csrc = (lane & 7) ^ lrow;            // source chunk for slot lane&7
  const int rbase = w * 32;                      // this wave's staging rows

  f32x4 acc[4][4];
  #pragma unroll
  for (int i = 0; i < 4; ++i)
    #pragma unroll
    for (int j = 0; j < 4; ++j) acc[i][j] = (f32x4){0.f, 0.f, 0.f, 0.f};

  for (int kt = 0; kt < SEQ; kt += 64) {
    __syncthreads();
    #pragma unroll
    for (int i = 0; i < 4; ++i) {
      const int r = rbase + i * 8 + lrow;
      const size_t ga = (size_t)(m0 + r) * SEQ + kt + csrc * 8;
      const size_t gb = (size_t)(n0 + r) * SEQ + kt + csrc * 8;
      unsigned short* la = &((unsigned short*)0)[0]; (void)la;
      load_lds16(Ah + ga, &sAh[r * 64 + (lane & 7) * 8]);
      load_lds16(Al + ga, &sAl[r * 64 + (lane & 7) * 8]);
      load_lds16(Bh + gb, &sBh[r * 64 + (lane & 7) * 8]);
      load_lds16(Bl + gb, &sBl[r * 64 + (lane & 7) * 8]);
    }
    __syncthreads();
    #pragma unroll
    for (int kk = 0; kk < 2; ++kk) {
      const int slot = ((kk * 4 + (lane >> 4)) ^ (lane & 7)) * 8;
      bf16x8 ah[4], al[4], bh[4], bl[4];
      #pragma unroll
      for (int mi = 0; mi < 4; ++mi) {
        int off = (wm + mi * 16 + (lane & 15)) * 64 + slot;
        ah[mi] = *(const bf16x8*)&sAh[off];
        al[mi] = *(const bf16x8*)&sAl[off];
      }
      #pragma unroll
      for (int ni = 0; ni < 4; ++ni) {
        int off = (wn + ni * 16 + (lane & 15)) * 64 + slot;
        bh[ni] = *(const bf16x8*)&sBh[off];
        bl[ni] = *(const bf16x8*)&sBl[off];
      }
      #pragma unroll
      for (int mi = 0; mi < 4; ++mi)
        #pragma unroll
        for (int ni = 0; ni < 4; ++ni) {
          acc[mi][ni] = __builtin_amdgcn_mfma_f32_16x16x32_bf16(ah[mi], bh[ni], acc[mi][ni], 0, 0, 0);
          acc[mi][ni] = __builtin_amdgcn_mfma_f32_16x16x32_bf16(ah[mi], bl[ni], acc[mi][ni], 0, 0, 0);
          acc[mi][ni] = __builtin_amdgcn_mfma_f32_16x16x32_bf16(al[mi], bh[ni], acc[mi][ni], 0, 0, 0);
        }
    }
  }
  // epilogue: bias add + store.  C/D: col=lane&15, row=(lane>>4)*4+reg
  #pragma unroll
  for (int ni = 0; ni < 4; ++ni) {
    const int n = n0 + wn + ni * 16 + (lane & 15);
    const float bv = bias[n];
    #pragma unroll
    for (int mi = 0; mi < 4; ++mi) {
      const int m = m0 + wm + mi * 16 + (lane >> 4) * 4;
      #pragma unroll
      for (int r = 0; r < 4; ++r)
        emb[(size_t)(m + r) * DMODEL + n] = acc[mi][ni][r] + bv;
    }
  }
}

// ---------------------------------------------------------------------------
// gemm_emb (fp32 fallback, used only if ws_size too small for bf16 path)
// ---------------------------------------------------------------------------
__global__ __launch_bounds__(256) void gemm_emb(const float* __restrict__ x,
    const float* __restrict__ W, const float* __restrict__ bias,
    float* __restrict__ emb) {
  __shared__ float As[64][64];
  __shared__ float Ws[64][132];
  const int bs = blockIdx.y;
  const int n0 = blockIdx.x * 128;
  const int t = threadIdx.x;
  const int tx = t & 15;
  const int ty = t >> 4;
  float bv[8];
  #pragma unroll
  for (int j = 0; j < 8; ++j) bv[j] = bias[n0 + 8 * tx + j];
  float acc[4][8];
  #pragma unroll
  for (int i = 0; i < 4; ++i)
    #pragma unroll
    for (int j = 0; j < 8; ++j) acc[i][j] = 0.f;
  const float* xb = x + (size_t)bs * SEQ * NVAR;
  for (int k0 = 0; k0 < SEQ; k0 += 64) {
    __syncthreads();
    {
      const float4* src = (const float4*)(xb + (size_t)k0 * NVAR);
      float4* dst = (float4*)&As[0][0];
      #pragma unroll
      for (int r = 0; r < 4; ++r) dst[t + 256 * r] = src[t + 256 * r];
    }
    #pragma unroll
    for (int r = 0; r < 8; ++r) {
      int idx = t + 256 * r;
      int k4 = idx & 15, n = idx >> 4;
      float4 wv = *(const float4*)(W + (size_t)(n0 + n) * SEQ + k0 + 4 * k4);
      Ws[4 * k4 + 0][n] = wv.x; Ws[4 * k4 + 1][n] = wv.y;
      Ws[4 * k4 + 2][n] = wv.z; Ws[4 * k4 + 3][n] = wv.w;
    }
    __syncthreads();
    #pragma unroll 8
    for (int kk = 0; kk < 64; ++kk) {
      const float4 a  = *(const float4*)&As[kk][4 * ty];
      const float4 w0 = *(const float4*)&Ws[kk][8 * tx];
      const float4 w1 = *(const float4*)&Ws[kk][8 * tx + 4];
      const float av[4] = {a.x, a.y, a.z, a.w};
      const float wv[8] = {w0.x, w0.y, w0.z, w0.w, w1.x, w1.y, w1.z, w1.w};
      #pragma unroll
      for (int i = 0; i < 4; ++i)
        #pragma unroll
        for (int j = 0; j < 8; ++j)
          acc[i][j] = fmaf(av[i], wv[j], acc[i][j]);
    }
  }
  #pragma unroll
  for (int i = 0; i < 4; ++i) {
    int row = bs * NVAR + 4 * ty + i;
    float4 o0 = make_float4(acc[i][0] + bv[0], acc[i][1] + bv[1],
                            acc[i][2] + bv[2], acc[i][3] + bv[3]);
    float4 o1 = make_float4(acc[i][4] + bv[4], acc[i][5] + bv[5],
                            acc[i][6] + bv[6], acc[i][7] + bv[7]);
    *(float4*)(emb + (size_t)row * DMODEL + n0 + 8 * tx) = o0;
    *(float4*)(emb + (size_t)row * DMODEL + n0 + 8 * tx + 4) = o1;
  }
}

// ---------------------------------------------------------------------------
// assign_partial: partial[c][k][n] = sum_{d in chunk c} emb[n][d]*cent[k][d]
// ---------------------------------------------------------------------------
__global__ __launch_bounds__(256) void assign_partial(const float* __restrict__ emb,
    const float* __restrict__ cent, const int* __restrict__ done,
    float* __restrict__ partial) {
  if (*done) return;
  __shared__ float Es[32][268];
  __shared__ float Cs[32][76];
  const int p0 = blockIdx.x * 256;
  const int d0 = blockIdx.y * 64;
  const int t = threadIdx.x;
  const int ty = t & 31;
  const int tx = t >> 5;
  float acc[8][8];
  #pragma unroll
  for (int i = 0; i < 8; ++i)
    #pragma unroll
    for (int j = 0; j < 8; ++j) acc[i][j] = 0.f;
  for (int sd = 0; sd < 64; sd += 32) {
    __syncthreads();
    #pragma unroll
    for (int r = 0; r < 8; ++r) {
      int idx = t + 256 * r;
      int d4 = idx & 7, p = idx >> 3;
      float4 e = *(const float4*)(emb + (size_t)(p0 + p) * DMODEL + d0 + sd + 4 * d4);
      Es[4 * d4 + 0][p] = e.x; Es[4 * d4 + 1][p] = e.y;
      Es[4 * d4 + 2][p] = e.z; Es[4 * d4 + 3][p] = e.w;
    }
    #pragma unroll
    for (int r = 0; r < 2; ++r) {
      int idx = t + 256 * r;
      int d4 = idx & 7, k = idx >> 3;
      float4 c = *(const float4*)(cent + (size_t)k * DMODEL + d0 + sd + 4 * d4);
      Cs[4 * d4 + 0][k] = c.x; Cs[4 * d4 + 1][k] = c.y;
      Cs[4 * d4 + 2][k] = c.z; Cs[4 * d4 + 3][k] = c.w;
    }
    __syncthreads();
    #pragma unroll 4
    for (int dd = 0; dd < 32; ++dd) {
      const float4 e0 = *(const float4*)&Es[dd][8 * ty];
      const float4 e1 = *(const float4*)&Es[dd][8 * ty + 4];
      const float4 c0 = *(const float4*)&Cs[dd][8 * tx];
      const float4 c1 = *(const float4*)&Cs[dd][8 * tx + 4];
      const float ev[8] = {e0.x, e0.y, e0.z, e0.w, e1.x, e1.y, e1.z, e1.w};
      const float cv[8] = {c0.x, c0.y, c0.z, c0.w, c1.x, c1.y, c1.z, c1.w};
      #pragma unroll
      for (int i = 0; i < 8; ++i)
        #pragma unroll
        for (int j = 0; j < 8; ++j)
          acc[i][j] = fmaf(ev[i], cv[j], acc[i][j]);
    }
  }
  float* pb = partial + (size_t)blockIdx.y * (KC * NPT) + p0 + 8 * ty;
  #pragma unroll
  for (int j = 0; j < 8; ++j) {
    int k = 8 * tx + j;
    float4 v0 = make_float4(acc[0][j], acc[1][j], acc[2][j], acc[3][j]);
    float4 v1 = make_float4(acc[4][j], acc[5][j], acc[6][j], acc[7][j]);
    *(float4*)(pb + (size_t)k * NPT) = v0;
    *(float4*)(pb + (size_t)k * NPT + 4) = v1;
  }
}

// ---------------------------------------------------------------------------
// argmin_segsum
// ---------------------------------------------------------------------------
__global__ __launch_bounds__(256) void argmin_segsum(const float* __restrict__ partial,
    const float* __restrict__ cent_sq, const float* __restrict__ emb,
    const int* __restrict__ done, int* __restrict__ ids,
    float* __restrict__ psum, float* __restrict__ pcnt) {
  if (*done) return;
  __shared__ float sums[KC][DMODEL];
  __shared__ int ids_l[128];
  const int g = blockIdx.x, t = threadIdx.x;
  const int p0 = g * 128;
  if (t >= 128) {
    float4 z = make_float4(0.f, 0.f, 0.f, 0.f);
    float4* sz = (float4*)&sums[0][0];
    #pragma unroll
    for (int r = 0; r < 64; ++r) sz[(t - 128) + 128 * r] = z;
  } else {
    int p = p0 + t;
    float best = 1e30f; int bi = 0;
    for (int k = 0; k < KC; ++k) {
      float dot = 0.f;
      #pragma unroll
      for (int c = 0; c < 8; ++c)
        dot += partial[(size_t)c * (KC * NPT) + (size_t)k * NPT + p];
      float d2 = cent_sq[k] - 2.f * dot;
      if (d2 < best) { best = d2; bi = k; }
    }
    ids[p] = bi;
    ids_l[t] = bi;
  }
  __syncthreads();
  const int d0 = 2 * t;
  for (int p = 0; p < 128; ++p) {
    int id = ids_l[p];
    float2 e = *(const float2*)(emb + (size_t)(p0 + p) * DMODEL + d0);
    float2* s = (float2*)&sums[id][d0];
    float2 v = *s;
    v.x += e.x; v.y += e.y;
    *s = v;
  }
  __syncthreads();
  for (int k = 0; k < KC; ++k)
    *(float2*)(psum + ((size_t)g * KC + k) * DMODEL + d0) = *(const float2*)&sums[k][d0];
  if (t < KC) {
    int c = 0;
    for (int p = 0; p < 128; ++p) c += (ids_l[p] == t);
    pcnt[g * KC + t] = (float)c;
  }
}

// ---------------------------------------------------------------------------
// update_cent
// ---------------------------------------------------------------------------
__global__ __launch_bounds__(256) void update_cent(float* __restrict__ cent,
    const float* __restrict__ psum, const float* __restrict__ pcnt,
    int* __restrict__ done, float* __restrict__ cent_sq,
    float* __restrict__ shift2, int* __restrict__ ticket, int iter) {
  if (*done) return;
  const int k = blockIdx.x, t = threadIdx.x;
  __shared__ float red[256];
  __shared__ float cnt_s;
  if (t < 64) {
    float c = pcnt[t * KC + k];
    #pragma unroll
    for (int off = 32; off > 0; off >>= 1) c += __shfl_down(c, off, 64);
    if (t == 0) cnt_s = c;
  }
  __syncthreads();
  const float count = cnt_s;
  float l_sh = 0.f, l_sq = 0.f;
  #pragma unroll
  for (int rr = 0; rr < 2; ++rr) {
    int d = t + 256 * rr;
    float s = 0.f;
    for (int g = 0; g < 64; ++g)
      s += psum[((size_t)g * KC + k) * DMODEL + d];
    float oldv = cent[k * DMODEL + d];
    float newv = (count > 0.f) ? (s / fmaxf(count, 1.f)) : oldv;
    cent[k * DMODEL + d] = newv;
    float df = newv - oldv;
    l_sh += df * df;
    l_sq += newv * newv;
  }
  red[t] = l_sh; __syncthreads();
  for (int s = 128; s > 0; s >>= 1) { if (t < s) red[t] += red[t + s]; __syncthreads(); }
  float tot_sh = red[0]; __syncthreads();
  red[t] = l_sq; __syncthreads();
  for (int s = 128; s > 0; s >>= 1) { if (t < s) red[t] += red[t + s]; __syncthreads(); }
  if (t == 0) {
    cent_sq[k] = red[0];
    atomicAdd(shift2 + iter, tot_sh);
    __threadfence();
    int tk = atomicAdd(ticket + iter, 1);
    if (tk == 63) {
      float tot = atomicAdd(shift2 + iter, 0.f);
      if (sqrtf(tot) < 1e-4f) *done = 1;
    }
  }
}

// ---------------------------------------------------------------------------
// finalize
// ---------------------------------------------------------------------------
__global__ __launch_bounds__(256) void finalize_k(const int* __restrict__ ids,
    const float* __restrict__ cent, float* __restrict__ out) {
  int t = blockIdx.x * 256 + threadIdx.x;
  if (t < NPT * KC) {
    int n = t >> 6, k = t & 63;
    out[t] = (ids[n] == k) ? 1.f : 0.f;
  } else {
    int i = t - NPT * KC;
    if (i < KC * DMODEL) out[NPT * KC + i] = cent[i];
  }
}

// ---------------------------------------------------------------------------
extern "C" void kernel_launch(void* const* d_in, const int* in_sizes, int n_in,
                              void* d_out, int out_size, void* d_ws, size_t ws_size,
                              hipStream_t stream) {
  const float* x    = (const float*)d_in[0];
  const float* W    = (const float*)d_in[1];
  const float* bias = (const float*)d_in[2];
  const float* c0   = (const float*)d_in[3];
  float* out = (float*)d_out;

  float* emb_out = out + NPT * KC + KC * DMODEL;   // x_emb slice of d_out

  // ws layout (floats)
  float* w = (float*)d_ws;
  float* cent    = w;                       // 32768
  float* cent_sq = w + 32768;               // 64
  float* shift2  = w + 32832;               // 16
  float* pcnt    = w + 32848;               // 4096
  int*   done_f  = (int*)(w + 36944);       // 16
  int*   ticket  = (int*)(w + 36960);       // 16
  int*   ids     = (int*)(w + 36976);       // 8192
  float* big     = w + 45168;               // union region
  // loop phase:
  float* partial = big;                     // 4194304
  float* psum    = big + 4194304;           // 2097152
  // gemm phase (aliases partial/psum — disjoint lifetime):
  unsigned short* Wh = (unsigned short*)big;                    // 1048576 us
  unsigned short* Wl = (unsigned short*)(big + 524288);         // 1048576 us
  unsigned short* Xh = (unsigned short*)(big + 1048576);        // 16777216 us
  unsigned short* Xl = (unsigned short*)(big + 1048576 + 8388608);
  const size_t need = (size_t)(45168 + 1048576 + 16777216) * 4; // ~71.5 MB
  (void)n_in; (void)in_sizes; (void)out_size;

  init_k<<<KC, 256, 0, stream>>>(c0, cent, cent_sq, done_f, shift2, ticket);
  if (ws_size >= need) {
    conv_w<<<1024, 256, 0, stream>>>(W, Wh, Wl);
    conv_x<<<dim3(32, BSZ), 256, 0, stream>>>(x, Xh, Xl);
    gemm_mfma<<<dim3(4, 64), 256, 0, stream>>>(Xh, Xl, Wh, Wl, bias, emb_out);
  } else {
    gemm_emb<<<dim3(4, BSZ), 256, 0, stream>>>(x, W, bias, emb_out);
  }
  for (int it = 0; it < MAXIT; ++it) {
    assign_partial<<<dim3(32, 8), 256, 0, stream>>>(emb_out, cent, done_f, partial);
    argmin_segsum<<<KC, 256, 0, stream>>>(partial, cent_sq, emb_out, done_f,
                                          ids, psum, pcnt);
    update_cent<<<KC, 256, 0, stream>>>(cent, psum, pcnt, done_f, cent_sq,
                                        shift2, ticket, it);
  }
  finalize_k<<<2176, 256, 0, stream>>>(ids, cent, out);
}

// Round 3
// 504.328 us; speedup vs baseline: 1.8850x; 1.6422x over previous
//
#include <hip/hip_runtime.h>

#define SEQ 2048
#define NVAR 64
#define DMODEL 512
#define BSZ 128
#define KC 64
#define NPT (BSZ*NVAR)   /* 8192 points */
#define MAXIT 10

typedef __bf16 bf16x8 __attribute__((ext_vector_type(8)));
typedef float f32x4 __attribute__((ext_vector_type(4)));

__device__ __forceinline__ void load_lds16(const void* g, void* l) {
  __builtin_amdgcn_global_load_lds((const __attribute__((address_space(1))) void*)g,
                                   (__attribute__((address_space(3))) void*)l, 16, 0, 0);
}

__device__ __forceinline__ unsigned short bf16_rn(float x) {
  unsigned int u = __float_as_uint(x);
  u += 0x7fffu + ((u >> 16) & 1u);
  return (unsigned short)(u >> 16);
}

// ---------------------------------------------------------------------------
// init: cent/centh/centl from c0, cent_sq, zero flags.  grid 64, block 256.
// ---------------------------------------------------------------------------
__global__ __launch_bounds__(256) void init_k(const float* __restrict__ c0,
    float* __restrict__ cent, unsigned short* __restrict__ centh,
    unsigned short* __restrict__ centl, float* __restrict__ cent_sq,
    int* __restrict__ done, float* __restrict__ shift2, int* __restrict__ ticket) {
  const int k = blockIdx.x, t = threadIdx.x;
  __shared__ float red[256];
  float l = 0.f;
  #pragma unroll
  for (int rr = 0; rr < 2; ++rr) {
    int d = t + 256 * rr;
    float v = c0[k * DMODEL + d];
    cent[k * DMODEL + d] = v;
    unsigned short h = bf16_rn(v);
    centh[k * DMODEL + d] = h;
    centl[k * DMODEL + d] = bf16_rn(v - __uint_as_float((unsigned)h << 16));
    l += v * v;
  }
  red[t] = l; __syncthreads();
  for (int s = 128; s > 0; s >>= 1) { if (t < s) red[t] += red[t + s]; __syncthreads(); }
  if (t == 0) cent_sq[k] = red[0];
  if (k == 0 && t < MAXIT) { shift2[t] = 0.f; ticket[t] = 0; }
  if (k == 0 && t == 31) *done = 0;
}

// ---------------------------------------------------------------------------
// conv_w: W fp32 -> hi/lo bf16.  grid 1024 x 256.
// ---------------------------------------------------------------------------
__global__ __launch_bounds__(256) void conv_w(const float* __restrict__ W,
    unsigned short* __restrict__ Wh, unsigned short* __restrict__ Wl) {
  int i = (blockIdx.x * 256 + threadIdx.x) * 4;
  float4 v = *(const float4*)(W + i);
  ushort4 h, l;
  h.x = bf16_rn(v.x); l.x = bf16_rn(v.x - __uint_as_float((unsigned)h.x << 16));
  h.y = bf16_rn(v.y); l.y = bf16_rn(v.y - __uint_as_float((unsigned)h.y << 16));
  h.z = bf16_rn(v.z); l.z = bf16_rn(v.z - __uint_as_float((unsigned)h.z << 16));
  h.w = bf16_rn(v.w); l.w = bf16_rn(v.w - __uint_as_float((unsigned)h.w << 16));
  *(ushort4*)(Wh + i) = h;
  *(ushort4*)(Wl + i) = l;
}

// ---------------------------------------------------------------------------
// conv_x: x[bs][k][v] -> xt hi/lo [bs*64+v][k].  grid (32,128) x 256.
// ---------------------------------------------------------------------------
__global__ __launch_bounds__(256) void conv_x(const float* __restrict__ x,
    unsigned short* __restrict__ Xh, unsigned short* __restrict__ Xl) {
  __shared__ float tile[64 * 65];
  const int k0 = blockIdx.x * 64;
  const int bs = blockIdx.y;
  const int t = threadIdx.x;
  const float* xb = x + (size_t)bs * SEQ * NVAR + (size_t)k0 * NVAR;
  #pragma unroll
  for (int p = 0; p < 4; ++p) {
    int idx = t + 256 * p;
    int row = idx >> 4, c4 = (idx & 15) * 4;
    float4 v = *(const float4*)(xb + row * NVAR + c4);
    tile[row * 65 + c4 + 0] = v.x; tile[row * 65 + c4 + 1] = v.y;
    tile[row * 65 + c4 + 2] = v.z; tile[row * 65 + c4 + 3] = v.w;
  }
  __syncthreads();
  const int v = t >> 2;
  const int kc = (t & 3) * 16;
  unsigned short h[16], l[16];
  #pragma unroll
  for (int j = 0; j < 16; ++j) {
    float f = tile[(kc + j) * 65 + v];
    h[j] = bf16_rn(f);
    l[j] = bf16_rn(f - __uint_as_float((unsigned)h[j] << 16));
  }
  size_t off = (size_t)(bs * 64 + v) * SEQ + k0 + kc;
  *(uint4*)(Xh + off)     = *(uint4*)&h[0];
  *(uint4*)(Xh + off + 8) = *(uint4*)&h[8];
  *(uint4*)(Xl + off)     = *(uint4*)&l[0];
  *(uint4*)(Xl + off + 8) = *(uint4*)&l[8];
}

// ---------------------------------------------------------------------------
// gemm_mfma: emb = Xt·W^T + b, bf16x3 split.  Tile 64m x 256n, BK=64.
// grid (2 n, 128 m), 256 thr (4 waves; wave w = 64m x 64n at wn=w*64).
// ---------------------------------------------------------------------------
__global__ __launch_bounds__(256) void gemm_mfma(
    const unsigned short* __restrict__ Ah, const unsigned short* __restrict__ Al,
    const unsigned short* __restrict__ Bh, const unsigned short* __restrict__ Bl,
    const float* __restrict__ bias, float* __restrict__ emb) {
  __shared__ unsigned short sAh[64 * 64] __attribute__((aligned(16)));
  __shared__ unsigned short sAl[64 * 64] __attribute__((aligned(16)));
  __shared__ unsigned short sBh[256 * 64] __attribute__((aligned(16)));
  __shared__ unsigned short sBl[256 * 64] __attribute__((aligned(16)));
  const int t = threadIdx.x;
  const int w = t >> 6, lane = t & 63;
  const int m0 = blockIdx.y * 64;
  const int n0 = blockIdx.x * 256;
  const int wn = w * 64;
  const int lrow = lane >> 3, sl8 = lane & 7;
  const int csrc = sl8 ^ lrow;

  f32x4 acc[4][4];
  #pragma unroll
  for (int i = 0; i < 4; ++i)
    #pragma unroll
    for (int j = 0; j < 4; ++j) acc[i][j] = (f32x4){0.f, 0.f, 0.f, 0.f};

  for (int kt = 0; kt < SEQ; kt += 64) {
    __syncthreads();
    #pragma unroll
    for (int i = 0; i < 2; ++i) {
      const int r = w * 16 + i * 8 + lrow;
      const size_t ga = (size_t)(m0 + r) * SEQ + kt + csrc * 8;
      load_lds16(Ah + ga, &sAh[r * 64 + sl8 * 8]);
      load_lds16(Al + ga, &sAl[r * 64 + sl8 * 8]);
    }
    #pragma unroll
    for (int i = 0; i < 8; ++i) {
      const int r = w * 64 + i * 8 + lrow;
      const size_t gb = (size_t)(n0 + r) * SEQ + kt + csrc * 8;
      load_lds16(Bh + gb, &sBh[r * 64 + sl8 * 8]);
      load_lds16(Bl + gb, &sBl[r * 64 + sl8 * 8]);
    }
    __syncthreads();
    #pragma unroll
    for (int kk = 0; kk < 2; ++kk) {
      const int sl = ((kk * 4 + (lane >> 4)) ^ (lane & 7)) * 8;
      bf16x8 ah[4], al[4], bh[4], bl[4];
      #pragma unroll
      for (int mi = 0; mi < 4; ++mi) {
        int off = (mi * 16 + (lane & 15)) * 64 + sl;
        ah[mi] = *(const bf16x8*)&sAh[off];
        al[mi] = *(const bf16x8*)&sAl[off];
      }
      #pragma unroll
      for (int ni = 0; ni < 4; ++ni) {
        int off = (wn + ni * 16 + (lane & 15)) * 64 + sl;
        bh[ni] = *(const bf16x8*)&sBh[off];
        bl[ni] = *(const bf16x8*)&sBl[off];
      }
      #pragma unroll
      for (int mi = 0; mi < 4; ++mi)
        #pragma unroll
        for (int ni = 0; ni < 4; ++ni) {
          acc[mi][ni] = __builtin_amdgcn_mfma_f32_16x16x32_bf16(ah[mi], bh[ni], acc[mi][ni], 0, 0, 0);
          acc[mi][ni] = __builtin_amdgcn_mfma_f32_16x16x32_bf16(ah[mi], bl[ni], acc[mi][ni], 0, 0, 0);
          acc[mi][ni] = __builtin_amdgcn_mfma_f32_16x16x32_bf16(al[mi], bh[ni], acc[mi][ni], 0, 0, 0);
        }
    }
  }
  #pragma unroll
  for (int ni = 0; ni < 4; ++ni) {
    const int n = n0 + wn + ni * 16 + (lane & 15);
    const float bv = bias[n];
    #pragma unroll
    for (int mi = 0; mi < 4; ++mi) {
      const int m = m0 + mi * 16 + (lane >> 4) * 4;
      #pragma unroll
      for (int r = 0; r < 4; ++r)
        emb[(size_t)(m + r) * DMODEL + n] = acc[mi][ni][r] + bv;
    }
  }
}

// ---------------------------------------------------------------------------
// gemm_emb: fp32 fallback (only if ws too small).
// ---------------------------------------------------------------------------
__global__ __launch_bounds__(256) void gemm_emb(const float* __restrict__ x,
    const float* __restrict__ W, const float* __restrict__ bias,
    float* __restrict__ emb) {
  __shared__ float As[64][64];
  __shared__ float Ws[64][132];
  const int bs = blockIdx.y;
  const int n0 = blockIdx.x * 128;
  const int t = threadIdx.x;
  const int tx = t & 15, ty = t >> 4;
  float bv[8];
  #pragma unroll
  for (int j = 0; j < 8; ++j) bv[j] = bias[n0 + 8 * tx + j];
  float acc[4][8];
  #pragma unroll
  for (int i = 0; i < 4; ++i)
    #pragma unroll
    for (int j = 0; j < 8; ++j) acc[i][j] = 0.f;
  const float* xb = x + (size_t)bs * SEQ * NVAR;
  for (int k0 = 0; k0 < SEQ; k0 += 64) {
    __syncthreads();
    {
      const float4* src = (const float4*)(xb + (size_t)k0 * NVAR);
      float4* dst = (float4*)&As[0][0];
      #pragma unroll
      for (int r = 0; r < 4; ++r) dst[t + 256 * r] = src[t + 256 * r];
    }
    #pragma unroll
    for (int r = 0; r < 8; ++r) {
      int idx = t + 256 * r;
      int k4 = idx & 15, n = idx >> 4;
      float4 wv = *(const float4*)(W + (size_t)(n0 + n) * SEQ + k0 + 4 * k4);
      Ws[4 * k4 + 0][n] = wv.x; Ws[4 * k4 + 1][n] = wv.y;
      Ws[4 * k4 + 2][n] = wv.z; Ws[4 * k4 + 3][n] = wv.w;
    }
    __syncthreads();
    #pragma unroll 8
    for (int kk = 0; kk < 64; ++kk) {
      const float4 a  = *(const float4*)&As[kk][4 * ty];
      const float4 w0 = *(const float4*)&Ws[kk][8 * tx];
      const float4 w1 = *(const float4*)&Ws[kk][8 * tx + 4];
      const float av[4] = {a.x, a.y, a.z, a.w};
      const float wv[8] = {w0.x, w0.y, w0.z, w0.w, w1.x, w1.y, w1.z, w1.w};
      #pragma unroll
      for (int i = 0; i < 4; ++i)
        #pragma unroll
        for (int j = 0; j < 8; ++j)
          acc[i][j] = fmaf(av[i], wv[j], acc[i][j]);
    }
  }
  #pragma unroll
  for (int i = 0; i < 4; ++i) {
    int row = bs * NVAR + 4 * ty + i;
    float4 o0 = make_float4(acc[i][0] + bv[0], acc[i][1] + bv[1],
                            acc[i][2] + bv[2], acc[i][3] + bv[3]);
    float4 o1 = make_float4(acc[i][4] + bv[4], acc[i][5] + bv[5],
                            acc[i][6] + bv[6], acc[i][7] + bv[7]);
    *(float4*)(emb + (size_t)row * DMODEL + n0 + 8 * tx) = o0;
    *(float4*)(emb + (size_t)row * DMODEL + n0 + 8 * tx + 4) = o1;
  }
}

// ---------------------------------------------------------------------------
// conv_et: emb fp32 -> Ehi/Elo [p][d] AND Ethi/Etlo [d][p] (LDS transpose).
// grid (8 d-tiles, 128 p-tiles) x 256.
// ---------------------------------------------------------------------------
__global__ __launch_bounds__(256) void conv_et(const float* __restrict__ emb,
    unsigned short* __restrict__ Eh, unsigned short* __restrict__ El,
    unsigned short* __restrict__ Eth, unsigned short* __restrict__ Etl) {
  __shared__ unsigned short Lh[64][72];
  __shared__ unsigned short Ll[64][72];
  const int d0 = blockIdx.x * 64;
  const int p0 = blockIdx.y * 64;
  const int t = threadIdx.x;
  #pragma unroll
  for (int q = 0; q < 2; ++q) {
    int idx = t + 256 * q;
    int r = idx >> 3, c = idx & 7;
    const float* src = emb + (size_t)(p0 + r) * DMODEL + d0 + c * 8;
    float4 v0 = *(const float4*)src;
    float4 v1 = *(const float4*)(src + 4);
    unsigned short h[8], l[8];
    const float vv[8] = {v0.x, v0.y, v0.z, v0.w, v1.x, v1.y, v1.z, v1.w};
    #pragma unroll
    for (int j = 0; j < 8; ++j) {
      h[j] = bf16_rn(vv[j]);
      l[j] = bf16_rn(vv[j] - __uint_as_float((unsigned)h[j] << 16));
    }
    size_t eo = (size_t)(p0 + r) * DMODEL + d0 + c * 8;
    *(uint4*)(Eh + eo) = *(uint4*)&h[0];
    *(uint4*)(El + eo) = *(uint4*)&l[0];
    *(uint4*)&Lh[r][c * 8] = *(uint4*)&h[0];
    *(uint4*)&Ll[r][c * 8] = *(uint4*)&l[0];
  }
  __syncthreads();
  #pragma unroll
  for (int q = 0; q < 2; ++q) {
    int idx = t + 256 * q;
    int dd = idx >> 3, pc = idx & 7;
    unsigned short h[8], l[8];
    #pragma unroll
    for (int j = 0; j < 8; ++j) {
      h[j] = Lh[pc * 8 + j][dd];
      l[j] = Ll[pc * 8 + j][dd];
    }
    size_t to = (size_t)(d0 + dd) * NPT + p0 + pc * 8;
    *(uint4*)(Eth + to) = *(uint4*)&h[0];
    *(uint4*)(Etl + to) = *(uint4*)&l[0];
  }
}

// ---------------------------------------------------------------------------
// k1 assign: D[p][k] = csq[k] - 2*E·cent^T (3-term bf16 MFMA), argmin, counts.
// grid 128 (64 p each), block 128 (2 waves; wave = 32p x 64k).
// ---------------------------------------------------------------------------
__global__ __launch_bounds__(128) void k1_assign(
    const unsigned short* __restrict__ Eh, const unsigned short* __restrict__ El,
    const unsigned short* __restrict__ Ch, const unsigned short* __restrict__ Cl,
    const float* __restrict__ cent_sq, const int* __restrict__ done,
    int* __restrict__ ids, float* __restrict__ pcnt) {
  if (*done) return;
  __shared__ unsigned short sEh[64 * 64] __attribute__((aligned(16)));
  __shared__ unsigned short sEl[64 * 64] __attribute__((aligned(16)));
  __shared__ unsigned short sCh[64 * 64] __attribute__((aligned(16)));
  __shared__ unsigned short sCl[64 * 64] __attribute__((aligned(16)));
  __shared__ float Dmat[64][65];
  __shared__ float csq_l[64];
  __shared__ int cnt_l[64];
  const int t = threadIdx.x;
  const int w = t >> 6, lane = t & 63;
  const int p0 = blockIdx.x * 64;
  const int lrow = lane >> 3, sl8 = lane & 7;
  const int csrc = sl8 ^ lrow;
  if (t < 64) { csq_l[t] = cent_sq[t]; cnt_l[t] = 0; }

  f32x4 acc[2][4];
  #pragma unroll
  for (int i = 0; i < 2; ++i)
    #pragma unroll
    for (int j = 0; j < 4; ++j) acc[i][j] = (f32x4){0.f, 0.f, 0.f, 0.f};

  for (int kt = 0; kt < DMODEL; kt += 64) {
    __syncthreads();
    #pragma unroll
    for (int i = 0; i < 4; ++i) {
      const int r = w * 32 + i * 8 + lrow;          // 0..63
      const size_t ga = (size_t)(p0 + r) * DMODEL + kt + csrc * 8;
      const size_t gc = (size_t)r * DMODEL + kt + csrc * 8;
      load_lds16(Eh + ga, &sEh[r * 64 + sl8 * 8]);
      load_lds16(El + ga, &sEl[r * 64 + sl8 * 8]);
      load_lds16(Ch + gc, &sCh[r * 64 + sl8 * 8]);
      load_lds16(Cl + gc, &sCl[r * 64 + sl8 * 8]);
    }
    __syncthreads();
    #pragma unroll
    for (int kk = 0; kk < 2; ++kk) {
      const int sl = ((kk * 4 + (lane >> 4)) ^ (lane & 7)) * 8;
      bf16x8 eh[2], el[2], ch[4], cl[4];
      #pragma unroll
      for (int mi = 0; mi < 2; ++mi) {
        int off = (w * 32 + mi * 16 + (lane & 15)) * 64 + sl;
        eh[mi] = *(const bf16x8*)&sEh[off];
        el[mi] = *(const bf16x8*)&sEl[off];
      }
      #pragma unroll
      for (int ni = 0; ni < 4; ++ni) {
        int off = (ni * 16 + (lane & 15)) * 64 + sl;
        ch[ni] = *(const bf16x8*)&sCh[off];
        cl[ni] = *(const bf16x8*)&sCl[off];
      }
      #pragma unroll
      for (int mi = 0; mi < 2; ++mi)
        #pragma unroll
        for (int ni = 0; ni < 4; ++ni) {
          acc[mi][ni] = __builtin_amdgcn_mfma_f32_16x16x32_bf16(eh[mi], ch[ni], acc[mi][ni], 0, 0, 0);
          acc[mi][ni] = __builtin_amdgcn_mfma_f32_16x16x32_bf16(eh[mi], cl[ni], acc[mi][ni], 0, 0, 0);
          acc[mi][ni] = __builtin_amdgcn_mfma_f32_16x16x32_bf16(el[mi], ch[ni], acc[mi][ni], 0, 0, 0);
        }
    }
  }
  #pragma unroll
  for (int mi = 0; mi < 2; ++mi)
    #pragma unroll
    for (int ni = 0; ni < 4; ++ni) {
      const int p = w * 32 + mi * 16 + (lane >> 4) * 4;
      const int k = ni * 16 + (lane & 15);
      const float csq = csq_l[k];
      #pragma unroll
      for (int r = 0; r < 4; ++r)
        Dmat[p + r][k] = csq - 2.f * acc[mi][ni][r];
    }
  __syncthreads();
  if (t < 64) {
    float best = Dmat[t][0]; int bi = 0;
    #pragma unroll 8
    for (int k = 1; k < KC; ++k) {
      float v = Dmat[t][k];
      if (v < best) { best = v; bi = k; }
    }
    ids[p0 + t] = bi;
    atomicAdd(&cnt_l[bi], 1);
  }
  __syncthreads();
  if (t < 64) pcnt[blockIdx.x * KC + t] = (float)cnt_l[t];
}

// ---------------------------------------------------------------------------
// k2 segsum: psum[g][k][d] = sum_p onehot[k][p] * emb[p][d] via bf16 MFMA
// (exact: OH in {0,1}, fp32 accumulate, fixed order -> deterministic).
// grid (4 d-quarters, 64 p-groups of 128), block 256 (4 waves; wave = 64k x 32d).
// ---------------------------------------------------------------------------
__global__ __launch_bounds__(256) void k2_segsum(
    const unsigned short* __restrict__ Eth, const unsigned short* __restrict__ Etl,
    const int* __restrict__ ids, const int* __restrict__ done,
    float* __restrict__ psum) {
  if (*done) return;
  __shared__ unsigned short sOH[64 * 136] __attribute__((aligned(16)));
  __shared__ unsigned short sTh[128 * 64] __attribute__((aligned(16)));
  __shared__ unsigned short sTl[128 * 64] __attribute__((aligned(16)));
  __shared__ int ids_l[128];
  const int t = threadIdx.x;
  const int w = t >> 6, lane = t & 63;
  const int dq = blockIdx.x, g = blockIdx.y;
  const int lrow = lane >> 3, sl8 = lane & 7;
  const int csrc = sl8 ^ lrow;

  if (t < 128) ids_l[t] = ids[g * 128 + t];
  __syncthreads();
  #pragma unroll
  for (int q = 0; q < 4; ++q) {
    int c = t * 4 + q;                  // 1024 chunks: 64 cl x 16 p-chunks
    int cl = c >> 4, pc = c & 15;
    unsigned short v[8];
    #pragma unroll
    for (int j = 0; j < 8; ++j)
      v[j] = (ids_l[pc * 8 + j] == cl) ? (unsigned short)0x3F80 : (unsigned short)0;
    *(uint4*)&sOH[cl * 136 + pc * 8] = *(uint4*)&v[0];
  }

  f32x4 acc[4][2];
  #pragma unroll
  for (int i = 0; i < 4; ++i)
    #pragma unroll
    for (int j = 0; j < 2; ++j) acc[i][j] = (f32x4){0.f, 0.f, 0.f, 0.f};

  for (int kt = 0; kt < 2; ++kt) {      // two 64-point K-tiles
    __syncthreads();
    #pragma unroll
    for (int i = 0; i < 4; ++i) {
      const int rr = w * 32 + i * 8 + lrow;   // d-row 0..127
      const size_t gt = (size_t)(dq * 128 + rr) * NPT + g * 128 + kt * 64 + csrc * 8;
      load_lds16(Eth + gt, &sTh[rr * 64 + sl8 * 8]);
      load_lds16(Etl + gt, &sTl[rr * 64 + sl8 * 8]);
    }
    __syncthreads();
    #pragma unroll
    for (int kk = 0; kk < 2; ++kk) {
      const int quad = lane >> 4;
      const int poff = kt * 64 + kk * 32 + quad * 8;
      bf16x8 a[4], bh[2], bl[2];
      #pragma unroll
      for (int mi = 0; mi < 4; ++mi)
        a[mi] = *(const bf16x8*)&sOH[(mi * 16 + (lane & 15)) * 136 + poff];
      const int sl = ((kk * 4 + quad) ^ (lane & 7)) * 8;
      #pragma unroll
      for (int ni = 0; ni < 2; ++ni) {
        int off = (w * 32 + ni * 16 + (lane & 15)) * 64 + sl;
        bh[ni] = *(const bf16x8*)&sTh[off];
        bl[ni] = *(const bf16x8*)&sTl[off];
      }
      #pragma unroll
      for (int mi = 0; mi < 4; ++mi)
        #pragma unroll
        for (int ni = 0; ni < 2; ++ni) {
          acc[mi][ni] = __builtin_amdgcn_mfma_f32_16x16x32_bf16(a[mi], bh[ni], acc[mi][ni], 0, 0, 0);
          acc[mi][ni] = __builtin_amdgcn_mfma_f32_16x16x32_bf16(a[mi], bl[ni], acc[mi][ni], 0, 0, 0);
        }
    }
  }
  #pragma unroll
  for (int mi = 0; mi < 4; ++mi)
    #pragma unroll
    for (int ni = 0; ni < 2; ++ni) {
      const int cl = mi * 16 + (lane >> 4) * 4;
      const int d = dq * 128 + w * 32 + ni * 16 + (lane & 15);
      #pragma unroll
      for (int r = 0; r < 4; ++r)
        psum[((size_t)g * KC + cl + r) * DMODEL + d] = acc[mi][ni][r];
    }
}

// ---------------------------------------------------------------------------
// k3 update: reduce psum (fixed order), new cent (+hi/lo), shift, done, csq.
// grid 64, block 256.
// ---------------------------------------------------------------------------
__global__ __launch_bounds__(256) void k3_update(float* __restrict__ cent,
    unsigned short* __restrict__ centh, unsigned short* __restrict__ centl,
    const float* __restrict__ psum, const float* __restrict__ pcnt,
    int* __restrict__ done, float* __restrict__ cent_sq,
    float* __restrict__ shift2, int* __restrict__ ticket, int iter) {
  if (*done) return;
  const int k = blockIdx.x, t = threadIdx.x;
  __shared__ float red[256];
  __shared__ float cnt_s;
  red[t] = (t < 128) ? pcnt[t * KC + k] : 0.f;
  __syncthreads();
  for (int s = 128; s > 0; s >>= 1) { if (t < s) red[t] += red[t + s]; __syncthreads(); }
  if (t == 0) cnt_s = red[0];
  __syncthreads();
  const float count = cnt_s;
  float l_sh = 0.f, l_sq = 0.f;
  #pragma unroll
  for (int rr = 0; rr < 2; ++rr) {
    int d = t + 256 * rr;
    float s = 0.f;
    for (int g = 0; g < 64; ++g)
      s += psum[((size_t)g * KC + k) * DMODEL + d];
    float oldv = cent[k * DMODEL + d];
    float newv = (count > 0.f) ? (s / fmaxf(count, 1.f)) : oldv;
    cent[k * DMODEL + d] = newv;
    unsigned short h = bf16_rn(newv);
    centh[k * DMODEL + d] = h;
    centl[k * DMODEL + d] = bf16_rn(newv - __uint_as_float((unsigned)h << 16));
    float df = newv - oldv;
    l_sh += df * df;
    l_sq += newv * newv;
  }
  red[t] = l_sh; __syncthreads();
  for (int s = 128; s > 0; s >>= 1) { if (t < s) red[t] += red[t + s]; __syncthreads(); }
  float tot_sh = red[0]; __syncthreads();
  red[t] = l_sq; __syncthreads();
  for (int s = 128; s > 0; s >>= 1) { if (t < s) red[t] += red[t + s]; __syncthreads(); }
  if (t == 0) {
    cent_sq[k] = red[0];
    atomicAdd(shift2 + iter, tot_sh);
    __threadfence();
    int tk = atomicAdd(ticket + iter, 1);
    if (tk == 63) {
      float tot = atomicAdd(shift2 + iter, 0.f);
      if (sqrtf(tot) < 1e-4f) *done = 1;
    }
  }
}

// ---------------------------------------------------------------------------
// finalize: one-hot prob + centroid copy.  grid 2176 x 256.
// ---------------------------------------------------------------------------
__global__ __launch_bounds__(256) void finalize_k(const int* __restrict__ ids,
    const float* __restrict__ cent, float* __restrict__ out) {
  int t = blockIdx.x * 256 + threadIdx.x;
  if (t < NPT * KC) {
    int n = t >> 6, k = t & 63;
    out[t] = (ids[n] == k) ? 1.f : 0.f;
  } else {
    int i = t - NPT * KC;
    if (i < KC * DMODEL) out[NPT * KC + i] = cent[i];
  }
}

// ---------------------------------------------------------------------------
extern "C" void kernel_launch(void* const* d_in, const int* in_sizes, int n_in,
                              void* d_out, int out_size, void* d_ws, size_t ws_size,
                              hipStream_t stream) {
  const float* x    = (const float*)d_in[0];
  const float* W    = (const float*)d_in[1];
  const float* bias = (const float*)d_in[2];
  const float* c0   = (const float*)d_in[3];
  float* out = (float*)d_out;
  float* emb_out = out + NPT * KC + KC * DMODEL;

  char* ws = (char*)d_ws;
  // loop phase (live after gemm finishes):
  unsigned short* Ehi  = (unsigned short*)(ws + 0);
  unsigned short* Elo  = (unsigned short*)(ws + 8388608);
  unsigned short* Eth  = (unsigned short*)(ws + 16777216);
  unsigned short* Etl  = (unsigned short*)(ws + 25165824);
  float* psum    = (float*)(ws + 33554432);
  float* cent    = (float*)(ws + 41943040);
  unsigned short* centh = (unsigned short*)(ws + 42074112);
  unsigned short* centl = (unsigned short*)(ws + 42139648);
  float* cent_sq = (float*)(ws + 42205184);
  float* shift2  = (float*)(ws + 42205440);
  int*   ticket  = (int*)(ws + 42205504);
  int*   done_f  = (int*)(ws + 42205568);
  float* pcnt    = (float*)(ws + 42205632);
  int*   ids     = (int*)(ws + 42238400);
  // gemm phase (aliases loop region; dead before init_k/conv_et run):
  unsigned short* Xh = (unsigned short*)(ws + 0);
  unsigned short* Xl = (unsigned short*)(ws + 33554432);
  unsigned short* Wh = (unsigned short*)(ws + 67108864);
  unsigned short* Wl = (unsigned short*)(ws + 69206016);
  const size_t need_fast = 71303168;
  (void)n_in; (void)in_sizes; (void)out_size;

  if (ws_size >= need_fast) {
    conv_w<<<1024, 256, 0, stream>>>(W, Wh, Wl);
    conv_x<<<dim3(32, BSZ), 256, 0, stream>>>(x, Xh, Xl);
    gemm_mfma<<<dim3(2, 128), 256, 0, stream>>>(Xh, Xl, Wh, Wl, bias, emb_out);
  } else {
    gemm_emb<<<dim3(4, BSZ), 256, 0, stream>>>(x, W, bias, emb_out);
  }
  init_k<<<KC, 256, 0, stream>>>(c0, cent, centh, centl, cent_sq, done_f, shift2, ticket);
  conv_et<<<dim3(8, 128), 256, 0, stream>>>(emb_out, Ehi, Elo, Eth, Etl);
  for (int it = 0; it < MAXIT; ++it) {
    k1_assign<<<128, 128, 0, stream>>>(Ehi, Elo, centh, centl, cent_sq, done_f, ids, pcnt);
    k2_segsum<<<dim3(4, 64), 256, 0, stream>>>(Eth, Etl, ids, done_f, psum);
    k3_update<<<KC, 256, 0, stream>>>(cent, centh, centl, psum, pcnt, done_f,
                                      cent_sq, shift2, ticket, it);
  }
  finalize_k<<<2176, 256, 0, stream>>>(ids, cent, out);
}